// Round 5
// baseline (460.827 us; speedup 1.0000x reference)
//
#include <hip/hip_runtime.h>
#include <hip/hip_fp16.h>

#define N_NODES 4096
#define DIMS 128
#define CHUNK 1024

typedef __attribute__((ext_vector_type(8))) short short8;
typedef __attribute__((ext_vector_type(4))) float f32x4;

static constexpr float BIGF = 1e9f;
static constexpr float EPSF = 1e-12f;
static constexpr unsigned long long KEY_INF = ~0ull;

// ---------------- helpers ----------------

__device__ inline unsigned short f32_to_bf16(float f) {
    unsigned u = __float_as_uint(f);
    unsigned r = (u + 0x7FFFu + ((u >> 16) & 1u)) >> 16;   // RNE
    return (unsigned short)r;
}

__device__ inline float half_bits_to_f32(unsigned short b) {
    __half h;
    __builtin_memcpy(&h, &b, 2);
    return __half2float(h);
}

__device__ inline unsigned long long shfl_xor_u64(unsigned long long v, int m) {
    int lo = __shfl_xor((int)(unsigned)(v & 0xFFFFFFFFull), m);
    int hi = __shfl_xor((int)(unsigned)(v >> 32), m);
    return ((unsigned long long)(unsigned)hi << 32) | (unsigned)lo;
}

__device__ inline unsigned long long u64min(unsigned long long a, unsigned long long b) {
    return a < b ? a : b;
}

__device__ inline float block_reduce_sum_256(float v) {
    __shared__ float s[4];
    __syncthreads();
    #pragma unroll
    for (int off = 32; off; off >>= 1) v += __shfl_xor(v, off);
    if ((threadIdx.x & 63) == 0) s[threadIdx.x >> 6] = v;
    __syncthreads();
    return s[0] + s[1] + s[2] + s[3];
}

// ---------------- prep: X -> bf16, row norms ----------------
__global__ __launch_bounds__(256) void prep_kernel(const float* __restrict__ X,
                                                   unsigned short* __restrict__ X16,
                                                   float* __restrict__ sq) {
    const int t = threadIdx.x;
    const int wave = t >> 6, lane = t & 63;
    const int row = blockIdx.x * 8 + wave * 2 + (lane >> 5);
    const int c4 = (lane & 31) * 4;
    float4 v = *(const float4*)&X[(size_t)row * DIMS + c4];
    float ss = v.x * v.x + v.y * v.y + v.z * v.z + v.w * v.w;
    #pragma unroll
    for (int m = 16; m; m >>= 1) ss += __shfl_xor(ss, m);
    if ((lane & 31) == 0) sq[row] = ss;
    ushort4 o;
    o.x = f32_to_bf16(v.x); o.y = f32_to_bf16(v.y);
    o.z = f32_to_bf16(v.z); o.w = f32_to_bf16(v.w);
    *(ushort4*)&X16[(size_t)row * DIMS + c4] = o;
}

// ---------------- distance matrix via MFMA ----------------
// 64x64 tile, 4 waves. D = sqrt(max(sq_i+sq_j-2G, EPS)) stored fp16.
__global__ __launch_bounds__(256) void dist_kernel(const unsigned short* __restrict__ X16,
                                                   const float* __restrict__ sq,
                                                   __half* __restrict__ D) {
    __shared__ __align__(16) unsigned short Abuf[64 * 128];
    __shared__ __align__(16) unsigned short Bbuf[64 * 128];
    const int bi = blockIdx.y * 64;
    const int bj = blockIdx.x * 64;
    const int t = threadIdx.x;

    #pragma unroll
    for (int p = 0; p < 4; p++) {
        int f = t + p * 256;
        int r = f >> 4, c8 = f & 15;
        int slot = c8 ^ (r & 7);
        uint4 va = *(const uint4*)&X16[(size_t)(bi + r) * DIMS + c8 * 8];
        *(uint4*)&Abuf[r * 128 + slot * 8] = va;
        uint4 vb = *(const uint4*)&X16[(size_t)(bj + r) * DIMS + c8 * 8];
        *(uint4*)&Bbuf[r * 128 + slot * 8] = vb;
    }
    __syncthreads();

    const int wave = t >> 6, lane = t & 63;
    const int l15 = lane & 15, kg = lane >> 4;

    const int rowA = wave * 16 + l15;
    short8 afrag[4];
    #pragma unroll
    for (int s = 0; s < 4; s++) {
        int c8 = s * 4 + kg;
        int slot = c8 ^ (rowA & 7);
        afrag[s] = *(const short8*)&Abuf[rowA * 128 + slot * 8];
    }

    f32x4 acc[4] = {};
    #pragma unroll
    for (int n = 0; n < 4; n++) {
        const int rowB = n * 16 + l15;
        #pragma unroll
        for (int s = 0; s < 4; s++) {
            int c8 = s * 4 + kg;
            int slot = c8 ^ (rowB & 7);
            short8 bfrag = *(const short8*)&Bbuf[rowB * 128 + slot * 8];
            acc[n] = __builtin_amdgcn_mfma_f32_16x16x32_bf16(afrag[s], bfrag, acc[n], 0, 0, 0);
        }
    }

    const int r0 = wave * 16 + kg * 4;
    float sqi[4];
    #pragma unroll
    for (int rr = 0; rr < 4; rr++) sqi[rr] = sq[bi + r0 + rr];
    #pragma unroll
    for (int n = 0; n < 4; n++) {
        const int col = bj + n * 16 + l15;
        const float sqj = sq[col];
        #pragma unroll
        for (int rr = 0; rr < 4; rr++) {
            float d2 = sqi[rr] + sqj - 2.0f * acc[n][rr];
            float dd = sqrtf(fmaxf(d2, EPSF));
            D[(size_t)(bi + r0 + rr) * N_NODES + col] = __float2half(dd);
        }
    }
}

// ---------------- Boruvka MST ----------------
// key = (fp16_bits << 24) | (min(i,j)<<12 | max(i,j)); fp16 bit order is
// monotone for nonneg values -> strict total edge order -> unique MST;
// sorted death multiset is invariant to tie-breaking anyway.

__global__ __launch_bounds__(1024) void init_kernel(unsigned* __restrict__ comp,
                                                    unsigned long long* __restrict__ best_comp,
                                                    unsigned* __restrict__ cnt,
                                                    unsigned* __restrict__ done) {
    int i = blockIdx.x * 1024 + threadIdx.x;
    if (i < 2 * N_NODES) {
        comp[i] = (unsigned)(i & (N_NODES - 1));
        best_comp[i] = KEY_INF;
    }
    if (i < 2) { cnt[i] = 0; done[i] = 0; }
}

// grid = (N_NODES/16, N_NODES/CHUNK, 2), block = 256 (4 waves).
// Each wave: 4 rows x CHUNK cols; one atomicMin(&bc[ci]) per row.
__global__ __launch_bounds__(256) void boruvka_scan(const unsigned short* __restrict__ D0,
                                                    const unsigned short* __restrict__ D1,
                                                    const unsigned* __restrict__ comp,
                                                    unsigned long long* __restrict__ best_comp,
                                                    const unsigned* __restrict__ done) {
    const int m = blockIdx.z;
    if (done[m]) return;
    const unsigned short* __restrict__ D = m ? D1 : D0;
    const unsigned* __restrict__ cm = comp + m * N_NODES;
    unsigned long long* bc = best_comp + m * N_NODES;

    __shared__ __align__(16) unsigned short s_c16[CHUNK];
    __shared__ unsigned s_rowc[16];

    const int t = threadIdx.x;
    const int col0 = blockIdx.y * CHUNK;
    const int rbase = blockIdx.x * 16;

    for (int i = t; i < CHUNK; i += 256) s_c16[i] = (unsigned short)cm[col0 + i];
    if (t < 16) s_rowc[t] = cm[rbase + t];
    __syncthreads();

    const int wave = t >> 6, lane = t & 63;

    for (int rr = 0; rr < 4; rr++) {
        const int r = rbase + wave * 4 + rr;
        const unsigned ci = s_rowc[wave * 4 + rr];
        const unsigned cirep = ci | (ci << 16);
        unsigned long long best = KEY_INF;
        const unsigned short* row = D + (size_t)r * N_NODES + col0;
        #pragma unroll
        for (int it = 0; it < CHUNK / 512; it++) {
            const int e0 = it * 512 + lane * 8;
            uint4 dv = *(const uint4*)&row[e0];
            uint4 cv = *(const uint4*)&s_c16[e0];
            unsigned diff = (cv.x ^ cirep) | (cv.y ^ cirep) | (cv.z ^ cirep) | (cv.w ^ cirep);
            if (diff) {
                unsigned dw[4] = {dv.x, dv.y, dv.z, dv.w};
                unsigned cw[4] = {cv.x, cv.y, cv.z, cv.w};
                #pragma unroll
                for (int h = 0; h < 4; h++) {
                    #pragma unroll
                    for (int q = 0; q < 2; q++) {
                        unsigned d16 = q ? (dw[h] >> 16) : (dw[h] & 0xFFFFu);
                        unsigned c16 = q ? (cw[h] >> 16) : (cw[h] & 0xFFFFu);
                        int j = col0 + e0 + h * 2 + q;
                        unsigned canon = (j > r) ? (((unsigned)r << 12) | (unsigned)j)
                                                 : (((unsigned)j << 12) | (unsigned)r);
                        if (c16 != (ci & 0xFFFFu)) {
                            unsigned long long key =
                                ((unsigned long long)d16 << 24) | canon;
                            best = u64min(best, key);
                        }
                    }
                }
            }
        }
        #pragma unroll
        for (int s = 32; s; s >>= 1) best = u64min(best, shfl_xor_u64(best, s));
        if (lane == 0 && best != KEY_INF) atomicMin(&bc[ci], best);
    }
}

// grid = 2 blocks (one per matrix), 1024 threads.
__global__ __launch_bounds__(1024) void boruvka_merge(unsigned* __restrict__ comp,
                                                      unsigned long long* __restrict__ best_comp,
                                                      float* __restrict__ deaths,
                                                      unsigned* __restrict__ cnt,
                                                      unsigned* __restrict__ done) {
    const int m = blockIdx.x;
    if (done[m]) return;
    unsigned* cm = comp + m * N_NODES;
    unsigned long long* bc = best_comp + m * N_NODES;
    float* dth = deaths + m * N_NODES;

    __shared__ unsigned s_comp[N_NODES];
    __shared__ unsigned s_par[N_NODES];
    __shared__ unsigned long long s_bc[N_NODES];
    __shared__ int s_changed;

    const int t = threadIdx.x;
    for (int i = t; i < N_NODES; i += 1024) {
        s_comp[i] = cm[i];
        s_par[i]  = (unsigned)i;
        s_bc[i]   = bc[i];
    }
    __syncthreads();

    // per-component winner edge from bc alone; emit once (dedupe mutual pairs)
    for (int i = t; i < N_NODES; i += 1024) {
        unsigned long long k = s_bc[i];
        if (k != KEY_INF) {
            unsigned canon = (unsigned)(k & 0xFFFFFFu);
            unsigned a = canon >> 12, b = canon & 0xFFFu;
            unsigned ca = s_comp[a], cb = s_comp[b];
            unsigned other = (ca == (unsigned)i) ? cb : ca;
            s_par[i] = other;
            bool mutual = (s_bc[other] == k);
            if (!mutual || (unsigned)i < other) {
                unsigned idx = atomicAdd(&cnt[m], 1u);
                dth[idx] = half_bits_to_f32((unsigned short)(k >> 24));
            }
        }
    }
    __syncthreads();

    // break 2-cycles: smaller id becomes root
    unsigned nv[4], pv[4];
    #pragma unroll
    for (int q = 0; q < 4; q++) {
        int i = t + q * 1024;
        unsigned p = s_par[i], pp = s_par[p];
        nv[q] = (pp == (unsigned)i) ? ((unsigned)i < p ? (unsigned)i : p) : p;
    }
    __syncthreads();
    #pragma unroll
    for (int q = 0; q < 4; q++) s_par[t + q * 1024] = nv[q];
    __syncthreads();

    // pointer jumping with convergence check
    for (;;) {
        bool ch = false;
        #pragma unroll
        for (int q = 0; q < 4; q++) {
            pv[q] = s_par[t + q * 1024];
            nv[q] = s_par[pv[q]];
            ch |= (nv[q] != pv[q]);
        }
        if (t == 0) s_changed = 0;
        __syncthreads();
        if (ch) s_changed = 1;
        #pragma unroll
        for (int q = 0; q < 4; q++) s_par[t + q * 1024] = nv[q];
        __syncthreads();
        if (!s_changed) break;
    }

    // relabel; reset per-component best for next round
    for (int i = t; i < N_NODES; i += 1024) {
        cm[i] = s_par[s_comp[i]];
        bc[i] = KEY_INF;
    }
    __syncthreads();
    if (t == 0) {
        unsigned c = atomicAdd(&cnt[m], 0u);
        if (c >= N_NODES - 1) done[m] = 1u;
    }
}

// ---------------- sort (bitonic, in LDS) ----------------
__global__ __launch_bounds__(1024) void sort_kernel(float* __restrict__ deaths) {
    float* d = deaths + blockIdx.x * N_NODES;
    __shared__ float s[N_NODES];
    const int t = threadIdx.x;
    for (int i = t; i < N_NODES - 1; i += 1024) s[i] = d[i];
    if (t == 0) s[N_NODES - 1] = BIGF;
    __syncthreads();
    for (int k = 2; k <= N_NODES; k <<= 1) {
        for (int j = k >> 1; j > 0; j >>= 1) {
            for (int i = t; i < N_NODES; i += 1024) {
                int p = i ^ j;
                if (p > i) {
                    float a = s[i], b = s[p];
                    bool asc = (i & k) == 0;
                    if ((a > b) == asc) { s[i] = b; s[p] = a; }
                }
            }
            __syncthreads();
        }
    }
    for (int i = t; i < N_NODES - 1; i += 1024) d[i] = s[i];
}

// ---------------- repr loss partials ----------------
__global__ __launch_bounds__(256) void repr_partial_kernel(const float* __restrict__ S,
                                                           const float* __restrict__ T,
                                                           float* __restrict__ partials) {
    const int tid = blockIdx.x * 256 + threadIdx.x;
    const int stride = gridDim.x * 256;
    const float4* S4 = (const float4*)S;
    const float4* T4 = (const float4*)T;
    float acc = 0.f;
    for (int i = tid; i < (N_NODES * DIMS) / 4; i += stride) {
        float4 a = S4[i], b = T4[i];
        float dx = a.x - b.x, dy = a.y - b.y, dz = a.z - b.z, dw = a.w - b.w;
        acc += dx * dx + dy * dy + dz * dz + dw * dw;
    }
    float s = block_reduce_sum_256(acc);
    if (threadIdx.x == 0) partials[blockIdx.x] = s;
}

// ---------------- finalize ----------------
__global__ __launch_bounds__(256) void finalize_kernel(const float* __restrict__ deaths,
                                                       const float* __restrict__ partials,
                                                       int n_partials,
                                                       float* __restrict__ out) {
    const float* ds = deaths;
    const float* dt = deaths + N_NODES;
    float a = 0.f;
    for (int i = threadIdx.x; i < N_NODES - 1; i += 256) {
        float d = ds[i] - dt[i];
        a += d * d;
    }
    float topo_sum = block_reduce_sum_256(a);
    float r = 0.f;
    for (int i = threadIdx.x; i < n_partials; i += 256) r += partials[i];
    float repr_sum = block_reduce_sum_256(r);
    if (threadIdx.x == 0) {
        float repr = repr_sum / (float)(N_NODES * DIMS);
        float topo = topo_sum / (float)(2 * (N_NODES - 1));
        out[0] = 0.5f * repr + 0.5f * topo;
        out[1] = repr;
        out[2] = topo;
    }
}

// ---------------- host ----------------

extern "C" void kernel_launch(void* const* d_in, const int* in_sizes, int n_in,
                              void* d_out, int out_size, void* d_ws, size_t ws_size,
                              hipStream_t stream) {
    const float* S = (const float*)d_in[0];
    const float* T = (const float*)d_in[1];
    float* out = (float*)d_out;

    const size_t nn = (size_t)N_NODES * N_NODES;
    char* p = (char*)d_ws;
    __half* Ds = (__half*)p;                   p += nn * 2;
    __half* Dt = (__half*)p;                   p += nn * 2;
    unsigned short* X16s = (unsigned short*)p; p += (size_t)N_NODES * DIMS * 2;
    unsigned short* X16t = (unsigned short*)p; p += (size_t)N_NODES * DIMS * 2;
    unsigned long long* best_comp = (unsigned long long*)p; p += 2 * N_NODES * 8;
    float*    sqs      = (float*)p;    p += N_NODES * 4;
    float*    sqt      = (float*)p;    p += N_NODES * 4;
    float*    deaths   = (float*)p;    p += 2 * N_NODES * 4;
    unsigned* comp     = (unsigned*)p; p += 2 * N_NODES * 4;
    float*    partials = (float*)p;    p += 256 * 4;
    unsigned* cnt      = (unsigned*)p; p += 2 * 4;
    unsigned* done     = (unsigned*)p;

    prep_kernel<<<N_NODES / 8, 256, 0, stream>>>(S, X16s, sqs);
    prep_kernel<<<N_NODES / 8, 256, 0, stream>>>(T, X16t, sqt);

    dim3 dg(N_NODES / 64, N_NODES / 64);
    dist_kernel<<<dg, 256, 0, stream>>>(X16s, sqs, Ds);
    dist_kernel<<<dg, 256, 0, stream>>>(X16t, sqt, Dt);

    repr_partial_kernel<<<256, 256, 0, stream>>>(S, T, partials);

    init_kernel<<<(2 * N_NODES + 1023) / 1024, 1024, 0, stream>>>(comp, best_comp, cnt, done);
    dim3 sg(N_NODES / 16, N_NODES / CHUNK, 2);
    for (int r = 0; r < 12; r++) {
        boruvka_scan<<<sg, 256, 0, stream>>>((const unsigned short*)Ds,
                                             (const unsigned short*)Dt,
                                             comp, best_comp, done);
        boruvka_merge<<<2, 1024, 0, stream>>>(comp, best_comp, deaths, cnt, done);
    }
    sort_kernel<<<2, 1024, 0, stream>>>(deaths);
    finalize_kernel<<<1, 256, 0, stream>>>(deaths, partials, 256, out);
}

// Round 6
// 242.061 us; speedup vs baseline: 1.9038x; 1.9038x over previous
//
#include <hip/hip_runtime.h>
#include <hip/hip_fp16.h>

#define N_NODES 4096
#define DIMS 128

typedef __attribute__((ext_vector_type(8))) short short8;
typedef __attribute__((ext_vector_type(4))) float f32x4;

static constexpr float BIGF = 1e9f;
static constexpr float EPSF = 1e-12f;
static constexpr unsigned long long KEY_INF = ~0ull;

// ---------------- helpers ----------------

__device__ inline unsigned short f32_to_bf16(float f) {
    unsigned u = __float_as_uint(f);
    unsigned r = (u + 0x7FFFu + ((u >> 16) & 1u)) >> 16;   // RNE
    return (unsigned short)r;
}

__device__ inline float half_bits_to_f32(unsigned short b) {
    __half h;
    __builtin_memcpy(&h, &b, 2);
    return __half2float(h);
}

__device__ inline unsigned long long shfl_xor_u64(unsigned long long v, int m) {
    int lo = __shfl_xor((int)(unsigned)(v & 0xFFFFFFFFull), m);
    int hi = __shfl_xor((int)(unsigned)(v >> 32), m);
    return ((unsigned long long)(unsigned)hi << 32) | (unsigned)lo;
}

__device__ inline unsigned long long u64min(unsigned long long a, unsigned long long b) {
    return a < b ? a : b;
}

__device__ inline float block_reduce_sum_256(float v) {
    __shared__ float s[4];
    __syncthreads();
    #pragma unroll
    for (int off = 32; off; off >>= 1) v += __shfl_xor(v, off);
    if ((threadIdx.x & 63) == 0) s[threadIdx.x >> 6] = v;
    __syncthreads();
    return s[0] + s[1] + s[2] + s[3];
}

// ---------------- prep: X -> bf16, row norms ----------------
__global__ __launch_bounds__(256) void prep_kernel(const float* __restrict__ X,
                                                   unsigned short* __restrict__ X16,
                                                   float* __restrict__ sq) {
    const int t = threadIdx.x;
    const int wave = t >> 6, lane = t & 63;
    const int row = blockIdx.x * 8 + wave * 2 + (lane >> 5);
    const int c4 = (lane & 31) * 4;
    float4 v = *(const float4*)&X[(size_t)row * DIMS + c4];
    float ss = v.x * v.x + v.y * v.y + v.z * v.z + v.w * v.w;
    #pragma unroll
    for (int m = 16; m; m >>= 1) ss += __shfl_xor(ss, m);
    if ((lane & 31) == 0) sq[row] = ss;
    ushort4 o;
    o.x = f32_to_bf16(v.x); o.y = f32_to_bf16(v.y);
    o.z = f32_to_bf16(v.z); o.w = f32_to_bf16(v.w);
    *(ushort4*)&X16[(size_t)row * DIMS + c4] = o;
}

// ---------------- distance matrix via MFMA ----------------
// 64x64 tile, 4 waves. D = sqrt(max(sq_i+sq_j-2G, EPS)) stored fp16.
__global__ __launch_bounds__(256) void dist_kernel(const unsigned short* __restrict__ X16,
                                                   const float* __restrict__ sq,
                                                   __half* __restrict__ D) {
    __shared__ __align__(16) unsigned short Abuf[64 * 128];
    __shared__ __align__(16) unsigned short Bbuf[64 * 128];
    const int bi = blockIdx.y * 64;
    const int bj = blockIdx.x * 64;
    const int t = threadIdx.x;

    #pragma unroll
    for (int p = 0; p < 4; p++) {
        int f = t + p * 256;
        int r = f >> 4, c8 = f & 15;
        int slot = c8 ^ (r & 7);
        uint4 va = *(const uint4*)&X16[(size_t)(bi + r) * DIMS + c8 * 8];
        *(uint4*)&Abuf[r * 128 + slot * 8] = va;
        uint4 vb = *(const uint4*)&X16[(size_t)(bj + r) * DIMS + c8 * 8];
        *(uint4*)&Bbuf[r * 128 + slot * 8] = vb;
    }
    __syncthreads();

    const int wave = t >> 6, lane = t & 63;
    const int l15 = lane & 15, kg = lane >> 4;

    const int rowA = wave * 16 + l15;
    short8 afrag[4];
    #pragma unroll
    for (int s = 0; s < 4; s++) {
        int c8 = s * 4 + kg;
        int slot = c8 ^ (rowA & 7);
        afrag[s] = *(const short8*)&Abuf[rowA * 128 + slot * 8];
    }

    f32x4 acc[4] = {};
    #pragma unroll
    for (int n = 0; n < 4; n++) {
        const int rowB = n * 16 + l15;
        #pragma unroll
        for (int s = 0; s < 4; s++) {
            int c8 = s * 4 + kg;
            int slot = c8 ^ (rowB & 7);
            short8 bfrag = *(const short8*)&Bbuf[rowB * 128 + slot * 8];
            acc[n] = __builtin_amdgcn_mfma_f32_16x16x32_bf16(afrag[s], bfrag, acc[n], 0, 0, 0);
        }
    }

    const int r0 = wave * 16 + kg * 4;
    float sqi[4];
    #pragma unroll
    for (int rr = 0; rr < 4; rr++) sqi[rr] = sq[bi + r0 + rr];
    #pragma unroll
    for (int n = 0; n < 4; n++) {
        const int col = bj + n * 16 + l15;
        const float sqj = sq[col];
        #pragma unroll
        for (int rr = 0; rr < 4; rr++) {
            float d2 = sqi[rr] + sqj - 2.0f * acc[n][rr];
            float dd = sqrtf(fmaxf(d2, EPSF));
            D[(size_t)(bi + r0 + rr) * N_NODES + col] = __float2half(dd);
        }
    }
}

// ---------------- Boruvka MST ----------------
// key = (fp16_bits << 24) | (min(i,j)<<12 | max(i,j)); fp16 bit order is
// monotone for nonneg values -> strict total edge order -> unique MST.
// best_row[r] caches row r's min foreign edge; it stays valid while its
// endpoint remains foreign (foreign set only shrinks under merging).
// Sentinel 0 = invalid/must-scan (d16==0 impossible: distances >= sqrt(eps)).

__global__ __launch_bounds__(1024) void init_kernel(unsigned* __restrict__ comp,
                                                    unsigned long long* __restrict__ best_comp,
                                                    unsigned long long* __restrict__ best_row,
                                                    unsigned* __restrict__ cnt,
                                                    unsigned* __restrict__ done) {
    int i = blockIdx.x * 1024 + threadIdx.x;
    if (i < 2 * N_NODES) {
        comp[i] = (unsigned)(i & (N_NODES - 1));
        best_comp[i] = KEY_INF;
        best_row[i] = 0ull;
    }
    if (i < 2) { cnt[i] = 0; done[i] = 0; }
}

// grid = (N_NODES/16, 2), block = 1024 (16 waves; one full row per wave).
__global__ __launch_bounds__(1024) void boruvka_scan(const unsigned short* __restrict__ D0,
                                                     const unsigned short* __restrict__ D1,
                                                     const unsigned* __restrict__ comp,
                                                     unsigned long long* __restrict__ best_row,
                                                     unsigned long long* __restrict__ best_comp,
                                                     const unsigned* __restrict__ done) {
    const int m = blockIdx.y;
    if (done[m]) return;
    const unsigned short* __restrict__ D = m ? D1 : D0;
    const unsigned* __restrict__ cm = comp + m * N_NODES;
    unsigned long long* br = best_row + m * N_NODES;
    unsigned long long* bc = best_comp + m * N_NODES;

    __shared__ __align__(16) unsigned short s_c16[N_NODES];   // 8 KB
    __shared__ unsigned s_rowc[16];

    const int t = threadIdx.x;
    {   // stage comps as u16 (uint4 loads, 8B LDS writes: conflict-free)
        const uint4* c4 = (const uint4*)cm;
        uint4 v = c4[t];
        ushort4 o;
        o.x = (unsigned short)v.x; o.y = (unsigned short)v.y;
        o.z = (unsigned short)v.z; o.w = (unsigned short)v.w;
        *(ushort4*)&s_c16[t * 4] = o;
    }
    const int rbase = blockIdx.x * 16;
    if (t < 16) s_rowc[t] = cm[rbase + t];
    __syncthreads();

    const int wave = t >> 6, lane = t & 63;
    const int r = rbase + wave;
    const unsigned ci = s_rowc[wave];
    const unsigned short ci16 = (unsigned short)ci;

    // cached-edge revalidation (whole wave takes same path)
    unsigned long long cached = br[r];
    bool valid = false;
    if (cached == KEY_INF) {
        valid = true;                       // row had no foreign cols: done
    } else if (cached != 0ull) {
        unsigned canon = (unsigned)(cached & 0xFFFFFFu);
        unsigned a = canon >> 12, b = canon & 0xFFFu;
        unsigned j = (a == (unsigned)r) ? b : a;
        valid = (s_c16[j] != ci16);
    }

    if (!valid) {
        unsigned long long best = KEY_INF;
        const unsigned short* row = D + (size_t)r * N_NODES;
        const unsigned cirep = (unsigned)ci16 | ((unsigned)ci16 << 16);
        #pragma unroll 2
        for (int it = 0; it < 8; it++) {
            const int e0 = it * 512 + lane * 8;
            uint4 dv = *(const uint4*)&row[e0];
            uint4 cv = *(const uint4*)&s_c16[e0];
            unsigned diff = (cv.x ^ cirep) | (cv.y ^ cirep) | (cv.z ^ cirep) | (cv.w ^ cirep);
            if (diff) {
                unsigned dw[4] = {dv.x, dv.y, dv.z, dv.w};
                unsigned cw[4] = {cv.x, cv.y, cv.z, cv.w};
                #pragma unroll
                for (int h = 0; h < 4; h++) {
                    #pragma unroll
                    for (int q = 0; q < 2; q++) {
                        unsigned d16 = q ? (dw[h] >> 16) : (dw[h] & 0xFFFFu);
                        unsigned c16 = q ? (cw[h] >> 16) : (cw[h] & 0xFFFFu);
                        int j = e0 + h * 2 + q;
                        unsigned canon = (j > r) ? (((unsigned)r << 12) | (unsigned)j)
                                                 : (((unsigned)j << 12) | (unsigned)r);
                        if (c16 != (unsigned)ci16) {
                            unsigned long long key =
                                ((unsigned long long)d16 << 24) | canon;
                            best = u64min(best, key);
                        }
                    }
                }
            }
        }
        #pragma unroll
        for (int s = 32; s; s >>= 1) best = u64min(best, shfl_xor_u64(best, s));
        cached = best;
        if (lane == 0) br[r] = best;
    }

    if (lane == 0 && cached != KEY_INF) atomicMin(&bc[ci], cached);
}

// grid = 2 blocks (one per matrix), 1024 threads. Root-chase instead of
// barrier-loop pointer jumping (forest after 2-cycle break -> terminates).
__global__ __launch_bounds__(1024) void boruvka_merge(unsigned* __restrict__ comp,
                                                      unsigned long long* __restrict__ best_comp,
                                                      float* __restrict__ deaths,
                                                      unsigned* __restrict__ cnt,
                                                      unsigned* __restrict__ done) {
    const int m = blockIdx.x;
    if (done[m]) return;
    unsigned* cm = comp + m * N_NODES;
    unsigned long long* bc = best_comp + m * N_NODES;
    float* dth = deaths + m * N_NODES;

    __shared__ unsigned s_comp[N_NODES];
    __shared__ unsigned s_par[N_NODES];
    __shared__ unsigned long long s_bc[N_NODES];

    const int t = threadIdx.x;
    for (int i = t; i < N_NODES; i += 1024) {
        s_comp[i] = cm[i];
        s_par[i]  = (unsigned)i;
        s_bc[i]   = bc[i];
    }
    __syncthreads();

    // hook: per-component winner edge from bc; emit once (dedupe mutual pairs)
    for (int i = t; i < N_NODES; i += 1024) {
        unsigned long long k = s_bc[i];
        if (k != KEY_INF) {
            unsigned canon = (unsigned)(k & 0xFFFFFFu);
            unsigned a = canon >> 12, b = canon & 0xFFFu;
            unsigned ca = s_comp[a], cb = s_comp[b];
            unsigned other = (ca == (unsigned)i) ? cb : ca;
            s_par[i] = other;
            bool mutual = (s_bc[other] == k);
            if (!mutual || (unsigned)i < other) {
                unsigned idx = atomicAdd(&cnt[m], 1u);
                dth[idx] = half_bits_to_f32((unsigned short)(k >> 24));
            }
        }
    }
    __syncthreads();

    // break 2-cycles: smaller id becomes root
    unsigned nv[4];
    #pragma unroll
    for (int q = 0; q < 4; q++) {
        int i = t + q * 1024;
        unsigned p = s_par[i], pp = s_par[p];
        nv[q] = (pp == (unsigned)i) ? ((unsigned)i < p ? (unsigned)i : p) : p;
    }
    __syncthreads();
    #pragma unroll
    for (int q = 0; q < 4; q++) s_par[t + q * 1024] = nv[q];
    __syncthreads();

    // chase roots (read-only traversal; forest guarantees termination)
    #pragma unroll
    for (int q = 0; q < 4; q++) {
        unsigned rt = (unsigned)(t + q * 1024);
        unsigned p = s_par[rt];
        while (p != rt) { rt = p; p = s_par[rt]; }
        nv[q] = rt;
    }
    __syncthreads();
    #pragma unroll
    for (int q = 0; q < 4; q++) s_par[t + q * 1024] = nv[q];
    __syncthreads();

    // relabel; reset per-component best for next round
    for (int i = t; i < N_NODES; i += 1024) {
        cm[i] = s_par[s_comp[i]];
        bc[i] = KEY_INF;
    }
    __syncthreads();
    if (t == 0) {
        unsigned c = atomicAdd(&cnt[m], 0u);
        if (c >= N_NODES - 1) done[m] = 1u;
    }
}

// ---------------- sort (hybrid bitonic: shuffles for j<=32) ----------------
__global__ __launch_bounds__(1024) void sort_kernel(float* __restrict__ deaths) {
    float* d = deaths + blockIdx.x * N_NODES;
    __shared__ float s[N_NODES];
    const int t = threadIdx.x;
    for (int i = t; i < N_NODES - 1; i += 1024) s[i] = d[i];
    if (t == 0) s[N_NODES - 1] = BIGF;
    __syncthreads();

    // k = 2..32 entirely in registers (partner t^j is in-wave for j<=32)
    {
        float v[4];
        #pragma unroll
        for (int q = 0; q < 4; q++) v[q] = s[t + q * 1024];
        #pragma unroll
        for (int k = 2; k <= 32; k <<= 1) {
            for (int j = k >> 1; j; j >>= 1) {
                #pragma unroll
                for (int q = 0; q < 4; q++) {
                    float o = __shfl_xor(v[q], j);
                    bool up  = (t & j) == 0;
                    bool asc = (((t + q * 1024) & k) == 0);
                    float lo = fminf(v[q], o), hi = fmaxf(v[q], o);
                    v[q] = (asc == up) ? lo : hi;
                }
            }
        }
        #pragma unroll
        for (int q = 0; q < 4; q++) s[t + q * 1024] = v[q];
    }
    __syncthreads();

    for (int k = 64; k <= N_NODES; k <<= 1) {
        for (int j = k >> 1; j >= 64; j >>= 1) {
            #pragma unroll
            for (int q = 0; q < 4; q++) {
                int i = t + q * 1024;
                int p = i ^ j;
                if (p > i) {
                    float a = s[i], b = s[p];
                    bool asc = (i & k) == 0;
                    if ((a > b) == asc) { s[i] = b; s[p] = a; }
                }
            }
            __syncthreads();
        }
        // j = 32..1 in registers
        float v[4];
        #pragma unroll
        for (int q = 0; q < 4; q++) v[q] = s[t + q * 1024];
        for (int j = 32; j; j >>= 1) {
            #pragma unroll
            for (int q = 0; q < 4; q++) {
                float o = __shfl_xor(v[q], j);
                bool up  = (t & j) == 0;
                bool asc = (((t + q * 1024) & k) == 0);
                float lo = fminf(v[q], o), hi = fmaxf(v[q], o);
                v[q] = (asc == up) ? lo : hi;
            }
        }
        #pragma unroll
        for (int q = 0; q < 4; q++) s[t + q * 1024] = v[q];
        __syncthreads();
    }
    for (int i = t; i < N_NODES - 1; i += 1024) d[i] = s[i];
}

// ---------------- repr loss partials ----------------
__global__ __launch_bounds__(256) void repr_partial_kernel(const float* __restrict__ S,
                                                           const float* __restrict__ T,
                                                           float* __restrict__ partials) {
    const int tid = blockIdx.x * 256 + threadIdx.x;
    const int stride = gridDim.x * 256;
    const float4* S4 = (const float4*)S;
    const float4* T4 = (const float4*)T;
    float acc = 0.f;
    for (int i = tid; i < (N_NODES * DIMS) / 4; i += stride) {
        float4 a = S4[i], b = T4[i];
        float dx = a.x - b.x, dy = a.y - b.y, dz = a.z - b.z, dw = a.w - b.w;
        acc += dx * dx + dy * dy + dz * dz + dw * dw;
    }
    float s = block_reduce_sum_256(acc);
    if (threadIdx.x == 0) partials[blockIdx.x] = s;
}

// ---------------- finalize ----------------
__global__ __launch_bounds__(256) void finalize_kernel(const float* __restrict__ deaths,
                                                       const float* __restrict__ partials,
                                                       int n_partials,
                                                       float* __restrict__ out) {
    const float* ds = deaths;
    const float* dt = deaths + N_NODES;
    float a = 0.f;
    for (int i = threadIdx.x; i < N_NODES - 1; i += 256) {
        float d = ds[i] - dt[i];
        a += d * d;
    }
    float topo_sum = block_reduce_sum_256(a);
    float r = 0.f;
    for (int i = threadIdx.x; i < n_partials; i += 256) r += partials[i];
    float repr_sum = block_reduce_sum_256(r);
    if (threadIdx.x == 0) {
        float repr = repr_sum / (float)(N_NODES * DIMS);
        float topo = topo_sum / (float)(2 * (N_NODES - 1));
        out[0] = 0.5f * repr + 0.5f * topo;
        out[1] = repr;
        out[2] = topo;
    }
}

// ---------------- host ----------------

extern "C" void kernel_launch(void* const* d_in, const int* in_sizes, int n_in,
                              void* d_out, int out_size, void* d_ws, size_t ws_size,
                              hipStream_t stream) {
    const float* S = (const float*)d_in[0];
    const float* T = (const float*)d_in[1];
    float* out = (float*)d_out;

    const size_t nn = (size_t)N_NODES * N_NODES;
    char* p = (char*)d_ws;
    __half* Ds = (__half*)p;                   p += nn * 2;
    __half* Dt = (__half*)p;                   p += nn * 2;
    unsigned short* X16s = (unsigned short*)p; p += (size_t)N_NODES * DIMS * 2;
    unsigned short* X16t = (unsigned short*)p; p += (size_t)N_NODES * DIMS * 2;
    unsigned long long* best_comp = (unsigned long long*)p; p += 2 * N_NODES * 8;
    unsigned long long* best_row  = (unsigned long long*)p; p += 2 * N_NODES * 8;
    float*    sqs      = (float*)p;    p += N_NODES * 4;
    float*    sqt      = (float*)p;    p += N_NODES * 4;
    float*    deaths   = (float*)p;    p += 2 * N_NODES * 4;
    unsigned* comp     = (unsigned*)p; p += 2 * N_NODES * 4;
    float*    partials = (float*)p;    p += 256 * 4;
    unsigned* cnt      = (unsigned*)p; p += 2 * 4;
    unsigned* done     = (unsigned*)p;

    prep_kernel<<<N_NODES / 8, 256, 0, stream>>>(S, X16s, sqs);
    prep_kernel<<<N_NODES / 8, 256, 0, stream>>>(T, X16t, sqt);

    dim3 dg(N_NODES / 64, N_NODES / 64);
    dist_kernel<<<dg, 256, 0, stream>>>(X16s, sqs, Ds);
    dist_kernel<<<dg, 256, 0, stream>>>(X16t, sqt, Dt);

    repr_partial_kernel<<<256, 256, 0, stream>>>(S, T, partials);

    init_kernel<<<(2 * N_NODES + 1023) / 1024, 1024, 0, stream>>>(comp, best_comp, best_row, cnt, done);
    dim3 sg(N_NODES / 16, 2);
    for (int r = 0; r < 12; r++) {
        boruvka_scan<<<sg, 1024, 0, stream>>>((const unsigned short*)Ds,
                                              (const unsigned short*)Dt,
                                              comp, best_row, best_comp, done);
        boruvka_merge<<<2, 1024, 0, stream>>>(comp, best_comp, deaths, cnt, done);
    }
    sort_kernel<<<2, 1024, 0, stream>>>(deaths);
    finalize_kernel<<<1, 256, 0, stream>>>(deaths, partials, 256, out);
}

// Round 7
// 235.622 us; speedup vs baseline: 1.9558x; 1.0273x over previous
//
#include <hip/hip_runtime.h>
#include <hip/hip_fp16.h>

#define N_NODES 4096
#define DIMS 128

typedef __attribute__((ext_vector_type(8))) short short8;
typedef __attribute__((ext_vector_type(4))) float f32x4;

static constexpr float BIGF = 1e9f;
static constexpr float EPSF = 1e-12f;
static constexpr unsigned long long KEY_INF = ~0ull;
static constexpr unsigned U32_INF = 0xFFFFFFFFu;

// ---------------- helpers ----------------

__device__ inline unsigned short f32_to_bf16(float f) {
    unsigned u = __float_as_uint(f);
    unsigned r = (u + 0x7FFFu + ((u >> 16) & 1u)) >> 16;   // RNE
    return (unsigned short)r;
}

__device__ inline float half_bits_to_f32(unsigned short b) {
    __half h;
    __builtin_memcpy(&h, &b, 2);
    return __half2float(h);
}

__device__ inline unsigned u32min(unsigned a, unsigned b) { return a < b ? a : b; }

__device__ inline float block_reduce_sum_256(float v) {
    __shared__ float s[4];
    __syncthreads();
    #pragma unroll
    for (int off = 32; off; off >>= 1) v += __shfl_xor(v, off);
    if ((threadIdx.x & 63) == 0) s[threadIdx.x >> 6] = v;
    __syncthreads();
    return s[0] + s[1] + s[2] + s[3];
}

// ---------------- prep: X -> bf16, row norms, repr partials ----------------
// grid 512 x 256: block handles 8 rows of BOTH S and T; half-wave per row.
__global__ __launch_bounds__(256) void prep_kernel(const float* __restrict__ S,
                                                   const float* __restrict__ T,
                                                   unsigned short* __restrict__ X16s,
                                                   unsigned short* __restrict__ X16t,
                                                   float* __restrict__ sqs,
                                                   float* __restrict__ sqt,
                                                   float* __restrict__ partials) {
    const int t = threadIdx.x;
    const int wave = t >> 6, lane = t & 63;
    const int row = blockIdx.x * 8 + wave * 2 + (lane >> 5);
    const int c4 = (lane & 31) * 4;
    const size_t off = (size_t)row * DIMS + c4;
    float4 a = *(const float4*)&S[off];
    float4 b = *(const float4*)&T[off];
    float sa = a.x * a.x + a.y * a.y + a.z * a.z + a.w * a.w;
    float sb = b.x * b.x + b.y * b.y + b.z * b.z + b.w * b.w;
    #pragma unroll
    for (int m = 16; m; m >>= 1) { sa += __shfl_xor(sa, m); sb += __shfl_xor(sb, m); }
    if ((lane & 31) == 0) { sqs[row] = sa; sqt[row] = sb; }
    ushort4 oa, ob;
    oa.x = f32_to_bf16(a.x); oa.y = f32_to_bf16(a.y);
    oa.z = f32_to_bf16(a.z); oa.w = f32_to_bf16(a.w);
    ob.x = f32_to_bf16(b.x); ob.y = f32_to_bf16(b.y);
    ob.z = f32_to_bf16(b.z); ob.w = f32_to_bf16(b.w);
    *(ushort4*)&X16s[off] = oa;
    *(ushort4*)&X16t[off] = ob;
    float dx = a.x - b.x, dy = a.y - b.y, dz = a.z - b.z, dw = a.w - b.w;
    float rs = block_reduce_sum_256(dx * dx + dy * dy + dz * dz + dw * dw);
    if (t == 0) partials[blockIdx.x] = rs;
}

// ---------------- init ----------------
__global__ __launch_bounds__(1024) void init_kernel(unsigned* __restrict__ comp,
                                                    unsigned long long* __restrict__ best_comp,
                                                    unsigned long long* __restrict__ best_row,
                                                    unsigned* __restrict__ cnt,
                                                    unsigned* __restrict__ done) {
    int i = blockIdx.x * 1024 + threadIdx.x;
    if (i < 2 * N_NODES) {
        comp[i] = (unsigned)(i & (N_NODES - 1));
        best_comp[i] = KEY_INF;
        best_row[i] = KEY_INF;                 // dist epilogue atomicMins real edges in
    }
    if (i < 2) { cnt[i] = 0; done[i] = 0; }
}

// ---------------- distance matrix via MFMA + fused row-min ----------------
// grid (64,64,2), 64x64 tile, 4 waves. D = sqrt(max(sq_i+sq_j-2G, EPS)) fp16.
// Epilogue also computes each row's min off-diagonal edge within the tile
// (u32 key (d16<<12)|col; within-row canon order == ascending col) and
// atomicMins the u64 (d16<<24)|canon key into best_row -> round-0 scan is free.
__global__ __launch_bounds__(256) void dist_kernel(const unsigned short* __restrict__ X16s,
                                                   const unsigned short* __restrict__ X16t,
                                                   const float* __restrict__ sqs,
                                                   const float* __restrict__ sqt,
                                                   __half* __restrict__ Ds,
                                                   __half* __restrict__ Dt,
                                                   unsigned long long* __restrict__ best_row) {
    const int m = blockIdx.z;
    const unsigned short* __restrict__ X16 = m ? X16t : X16s;
    const float* __restrict__ sq = m ? sqt : sqs;
    __half* __restrict__ D = m ? Dt : Ds;
    unsigned long long* br = best_row + m * N_NODES;

    __shared__ __align__(16) unsigned short Abuf[64 * 128];
    __shared__ __align__(16) unsigned short Bbuf[64 * 128];
    const int bi = blockIdx.y * 64;
    const int bj = blockIdx.x * 64;
    const int t = threadIdx.x;

    #pragma unroll
    for (int p = 0; p < 4; p++) {
        int f = t + p * 256;
        int r = f >> 4, c8 = f & 15;
        int slot = c8 ^ (r & 7);
        uint4 va = *(const uint4*)&X16[(size_t)(bi + r) * DIMS + c8 * 8];
        *(uint4*)&Abuf[r * 128 + slot * 8] = va;
        uint4 vb = *(const uint4*)&X16[(size_t)(bj + r) * DIMS + c8 * 8];
        *(uint4*)&Bbuf[r * 128 + slot * 8] = vb;
    }
    __syncthreads();

    const int wave = t >> 6, lane = t & 63;
    const int l15 = lane & 15, kg = lane >> 4;

    const int rowA = wave * 16 + l15;
    short8 afrag[4];
    #pragma unroll
    for (int s = 0; s < 4; s++) {
        int c8 = s * 4 + kg;
        int slot = c8 ^ (rowA & 7);
        afrag[s] = *(const short8*)&Abuf[rowA * 128 + slot * 8];
    }

    f32x4 acc[4] = {};
    #pragma unroll
    for (int n = 0; n < 4; n++) {
        const int rowB = n * 16 + l15;
        #pragma unroll
        for (int s = 0; s < 4; s++) {
            int c8 = s * 4 + kg;
            int slot = c8 ^ (rowB & 7);
            short8 bfrag = *(const short8*)&Bbuf[rowB * 128 + slot * 8];
            acc[n] = __builtin_amdgcn_mfma_f32_16x16x32_bf16(afrag[s], bfrag, acc[n], 0, 0, 0);
        }
    }

    const int r0 = wave * 16 + kg * 4;
    float sqi[4];
    #pragma unroll
    for (int rr = 0; rr < 4; rr++) sqi[rr] = sq[bi + r0 + rr];

    unsigned kmin[4] = {U32_INF, U32_INF, U32_INF, U32_INF};
    #pragma unroll
    for (int n = 0; n < 4; n++) {
        const int col = bj + n * 16 + l15;
        const float sqj = sq[col];
        #pragma unroll
        for (int rr = 0; rr < 4; rr++) {
            float d2 = sqi[rr] + sqj - 2.0f * acc[n][rr];
            float dd = sqrtf(fmaxf(d2, EPSF));
            __half h = __float2half(dd);
            D[(size_t)(bi + r0 + rr) * N_NODES + col] = h;
            unsigned key = ((unsigned)__half_as_ushort(h) << 12) | (unsigned)col;
            if ((bi + r0 + rr) != col) kmin[rr] = u32min(kmin[rr], key);
        }
    }
    // reduce across the 16 lanes sharing kg (xor 8,4,2,1 stays in-group)
    #pragma unroll
    for (int rr = 0; rr < 4; rr++) {
        unsigned k = kmin[rr];
        #pragma unroll
        for (int s = 8; s; s >>= 1) k = u32min(k, (unsigned)__shfl_xor((int)k, s));
        if (l15 == 0) {
            const unsigned row = (unsigned)(bi + r0 + rr);
            unsigned j = k & 0xFFFu, d16 = k >> 12;
            unsigned a = row < j ? row : j, b2 = row < j ? j : row;
            unsigned long long key64 =
                ((unsigned long long)d16 << 24) | ((unsigned long long)a << 12) | b2;
            atomicMin(&br[row], key64);
        }
    }
}

// ---------------- Boruvka scan ----------------
// grid = (N_NODES/16, 2), block = 1024 (16 waves; one full row per wave).
// best_row[r] caches row r's min foreign edge; valid while endpoint foreign.
__global__ __launch_bounds__(1024) void boruvka_scan(const unsigned short* __restrict__ D0,
                                                     const unsigned short* __restrict__ D1,
                                                     const unsigned* __restrict__ comp,
                                                     unsigned long long* __restrict__ best_row,
                                                     unsigned long long* __restrict__ best_comp,
                                                     const unsigned* __restrict__ done) {
    const int m = blockIdx.y;
    if (done[m]) return;
    const unsigned short* __restrict__ D = m ? D1 : D0;
    const unsigned* __restrict__ cm = comp + m * N_NODES;
    unsigned long long* br = best_row + m * N_NODES;
    unsigned long long* bc = best_comp + m * N_NODES;

    __shared__ __align__(16) unsigned short s_c16[N_NODES];   // 8 KB
    __shared__ unsigned s_rowc[16];

    const int t = threadIdx.x;
    {
        const uint4* c4 = (const uint4*)cm;
        uint4 v = c4[t];
        ushort4 o;
        o.x = (unsigned short)v.x; o.y = (unsigned short)v.y;
        o.z = (unsigned short)v.z; o.w = (unsigned short)v.w;
        *(ushort4*)&s_c16[t * 4] = o;
    }
    const int rbase = blockIdx.x * 16;
    if (t < 16) s_rowc[t] = cm[rbase + t];
    __syncthreads();

    const int wave = t >> 6, lane = t & 63;
    const int r = rbase + wave;
    const unsigned ci = s_rowc[wave];
    const unsigned short ci16 = (unsigned short)ci;

    unsigned long long cached = br[r];
    bool valid;
    if (cached == KEY_INF) {
        valid = true;                        // no foreign cols remain
    } else {
        unsigned canon = (unsigned)(cached & 0xFFFFFFu);
        unsigned a = canon >> 12, b = canon & 0xFFFu;
        unsigned j = (a == (unsigned)r) ? b : a;
        valid = (s_c16[j] != ci16);
    }

    if (!valid) {
        unsigned best32 = U32_INF;
        const unsigned short* row = D + (size_t)r * N_NODES;
        const unsigned cirep = (unsigned)ci16 | ((unsigned)ci16 << 16);
        #pragma unroll 4
        for (int it = 0; it < 8; it++) {
            const int e0 = it * 512 + lane * 8;
            uint4 dv = *(const uint4*)&row[e0];
            uint4 cv = *(const uint4*)&s_c16[e0];
            unsigned px = cv.x ^ cirep, py = cv.y ^ cirep;
            unsigned pz = cv.z ^ cirep, pw = cv.w ^ cirep;
            if (px | py | pz | pw) {
                unsigned dw4[4] = {dv.x, dv.y, dv.z, dv.w};
                unsigned pp[4] = {px, py, pz, pw};
                #pragma unroll
                for (int h = 0; h < 4; h++) {
                    unsigned j0 = (unsigned)(e0 + h * 2);
                    if (pp[h] & 0xFFFFu)
                        best32 = u32min(best32, ((dw4[h] & 0xFFFFu) << 12) | j0);
                    if (pp[h] >> 16)
                        best32 = u32min(best32, ((dw4[h] >> 16) << 12) | (j0 + 1));
                }
            }
        }
        #pragma unroll
        for (int s = 32; s; s >>= 1) best32 = u32min(best32, (unsigned)__shfl_xor((int)best32, s));
        if (lane == 0) {
            if (best32 != U32_INF) {
                unsigned j = best32 & 0xFFFu, d16 = best32 >> 12;
                unsigned a = (unsigned)r < j ? (unsigned)r : j;
                unsigned b2 = (unsigned)r < j ? j : (unsigned)r;
                cached = ((unsigned long long)d16 << 24) | ((unsigned long long)a << 12) | b2;
            } else {
                cached = KEY_INF;
            }
            br[r] = cached;
        }
        cached = __shfl(cached, 0, 64);
    }

    if (lane == 0 && cached != KEY_INF) atomicMin(&bc[ci], cached);
}

// ---------------- Boruvka merge ----------------
// grid = 2 blocks (one per matrix), 1024 threads.
__global__ __launch_bounds__(1024) void boruvka_merge(unsigned* __restrict__ comp,
                                                      unsigned long long* __restrict__ best_comp,
                                                      float* __restrict__ deaths,
                                                      unsigned* __restrict__ cnt,
                                                      unsigned* __restrict__ done) {
    const int m = blockIdx.x;
    if (done[m]) return;
    unsigned* cm = comp + m * N_NODES;
    unsigned long long* bc = best_comp + m * N_NODES;
    float* dth = deaths + m * N_NODES;

    __shared__ unsigned s_comp[N_NODES];
    __shared__ unsigned s_par[N_NODES];
    __shared__ unsigned long long s_bc[N_NODES];

    const int t = threadIdx.x;
    for (int i = t; i < N_NODES; i += 1024) {
        s_comp[i] = cm[i];
        s_par[i]  = (unsigned)i;
        s_bc[i]   = bc[i];
    }
    __syncthreads();

    for (int i = t; i < N_NODES; i += 1024) {
        unsigned long long k = s_bc[i];
        if (k != KEY_INF) {
            unsigned canon = (unsigned)(k & 0xFFFFFFu);
            unsigned a = canon >> 12, b = canon & 0xFFFu;
            unsigned ca = s_comp[a], cb = s_comp[b];
            unsigned other = (ca == (unsigned)i) ? cb : ca;
            s_par[i] = other;
            bool mutual = (s_bc[other] == k);
            if (!mutual || (unsigned)i < other) {
                unsigned idx = atomicAdd(&cnt[m], 1u);
                dth[idx] = half_bits_to_f32((unsigned short)(k >> 24));
            }
        }
    }
    __syncthreads();

    unsigned nv[4];
    #pragma unroll
    for (int q = 0; q < 4; q++) {
        int i = t + q * 1024;
        unsigned p = s_par[i], pp = s_par[p];
        nv[q] = (pp == (unsigned)i) ? ((unsigned)i < p ? (unsigned)i : p) : p;
    }
    __syncthreads();
    #pragma unroll
    for (int q = 0; q < 4; q++) s_par[t + q * 1024] = nv[q];
    __syncthreads();

    #pragma unroll
    for (int q = 0; q < 4; q++) {
        unsigned rt = (unsigned)(t + q * 1024);
        unsigned p = s_par[rt];
        while (p != rt) { rt = p; p = s_par[rt]; }
        nv[q] = rt;
    }
    __syncthreads();
    #pragma unroll
    for (int q = 0; q < 4; q++) s_par[t + q * 1024] = nv[q];
    __syncthreads();

    for (int i = t; i < N_NODES; i += 1024) {
        cm[i] = s_par[s_comp[i]];
        bc[i] = KEY_INF;
    }
    __syncthreads();
    if (t == 0) {
        unsigned c = atomicAdd(&cnt[m], 0u);
        if (c >= N_NODES - 1) done[m] = 1u;
    }
}

// ---------------- sort (hybrid bitonic: shuffles for j<=32) ----------------
__global__ __launch_bounds__(1024) void sort_kernel(float* __restrict__ deaths) {
    float* d = deaths + blockIdx.x * N_NODES;
    __shared__ float s[N_NODES];
    const int t = threadIdx.x;
    for (int i = t; i < N_NODES - 1; i += 1024) s[i] = d[i];
    if (t == 0) s[N_NODES - 1] = BIGF;
    __syncthreads();

    {
        float v[4];
        #pragma unroll
        for (int q = 0; q < 4; q++) v[q] = s[t + q * 1024];
        #pragma unroll
        for (int k = 2; k <= 32; k <<= 1) {
            for (int j = k >> 1; j; j >>= 1) {
                #pragma unroll
                for (int q = 0; q < 4; q++) {
                    float o = __shfl_xor(v[q], j);
                    bool up  = (t & j) == 0;
                    bool asc = (((t + q * 1024) & k) == 0);
                    float lo = fminf(v[q], o), hi = fmaxf(v[q], o);
                    v[q] = (asc == up) ? lo : hi;
                }
            }
        }
        #pragma unroll
        for (int q = 0; q < 4; q++) s[t + q * 1024] = v[q];
    }
    __syncthreads();

    for (int k = 64; k <= N_NODES; k <<= 1) {
        for (int j = k >> 1; j >= 64; j >>= 1) {
            #pragma unroll
            for (int q = 0; q < 4; q++) {
                int i = t + q * 1024;
                int p = i ^ j;
                if (p > i) {
                    float a = s[i], b = s[p];
                    bool asc = (i & k) == 0;
                    if ((a > b) == asc) { s[i] = b; s[p] = a; }
                }
            }
            __syncthreads();
        }
        float v[4];
        #pragma unroll
        for (int q = 0; q < 4; q++) v[q] = s[t + q * 1024];
        for (int j = 32; j; j >>= 1) {
            #pragma unroll
            for (int q = 0; q < 4; q++) {
                float o = __shfl_xor(v[q], j);
                bool up  = (t & j) == 0;
                bool asc = (((t + q * 1024) & k) == 0);
                float lo = fminf(v[q], o), hi = fmaxf(v[q], o);
                v[q] = (asc == up) ? lo : hi;
            }
        }
        #pragma unroll
        for (int q = 0; q < 4; q++) s[t + q * 1024] = v[q];
        __syncthreads();
    }
    for (int i = t; i < N_NODES - 1; i += 1024) d[i] = s[i];
}

// ---------------- finalize ----------------
__global__ __launch_bounds__(256) void finalize_kernel(const float* __restrict__ deaths,
                                                       const float* __restrict__ partials,
                                                       int n_partials,
                                                       float* __restrict__ out) {
    const float* ds = deaths;
    const float* dt = deaths + N_NODES;
    float a = 0.f;
    for (int i = threadIdx.x; i < N_NODES - 1; i += 256) {
        float d = ds[i] - dt[i];
        a += d * d;
    }
    float topo_sum = block_reduce_sum_256(a);
    float r = 0.f;
    for (int i = threadIdx.x; i < n_partials; i += 256) r += partials[i];
    float repr_sum = block_reduce_sum_256(r);
    if (threadIdx.x == 0) {
        float repr = repr_sum / (float)(N_NODES * DIMS);
        float topo = topo_sum / (float)(2 * (N_NODES - 1));
        out[0] = 0.5f * repr + 0.5f * topo;
        out[1] = repr;
        out[2] = topo;
    }
}

// ---------------- host ----------------

extern "C" void kernel_launch(void* const* d_in, const int* in_sizes, int n_in,
                              void* d_out, int out_size, void* d_ws, size_t ws_size,
                              hipStream_t stream) {
    const float* S = (const float*)d_in[0];
    const float* T = (const float*)d_in[1];
    float* out = (float*)d_out;

    const size_t nn = (size_t)N_NODES * N_NODES;
    char* p = (char*)d_ws;
    __half* Ds = (__half*)p;                   p += nn * 2;
    __half* Dt = (__half*)p;                   p += nn * 2;
    unsigned short* X16s = (unsigned short*)p; p += (size_t)N_NODES * DIMS * 2;
    unsigned short* X16t = (unsigned short*)p; p += (size_t)N_NODES * DIMS * 2;
    unsigned long long* best_comp = (unsigned long long*)p; p += 2 * N_NODES * 8;
    unsigned long long* best_row  = (unsigned long long*)p; p += 2 * N_NODES * 8;
    float*    sqs      = (float*)p;    p += N_NODES * 4;
    float*    sqt      = (float*)p;    p += N_NODES * 4;
    float*    deaths   = (float*)p;    p += 2 * N_NODES * 4;
    unsigned* comp     = (unsigned*)p; p += 2 * N_NODES * 4;
    float*    partials = (float*)p;    p += 512 * 4;
    unsigned* cnt      = (unsigned*)p; p += 2 * 4;
    unsigned* done     = (unsigned*)p;

    prep_kernel<<<N_NODES / 8, 256, 0, stream>>>(S, T, X16s, X16t, sqs, sqt, partials);
    init_kernel<<<(2 * N_NODES + 1023) / 1024, 1024, 0, stream>>>(comp, best_comp, best_row, cnt, done);

    dim3 dg(N_NODES / 64, N_NODES / 64, 2);
    dist_kernel<<<dg, 256, 0, stream>>>(X16s, X16t, sqs, sqt, Ds, Dt, best_row);

    dim3 sg(N_NODES / 16, 2);
    for (int r = 0; r < 12; r++) {
        boruvka_scan<<<sg, 1024, 0, stream>>>((const unsigned short*)Ds,
                                              (const unsigned short*)Dt,
                                              comp, best_row, best_comp, done);
        boruvka_merge<<<2, 1024, 0, stream>>>(comp, best_comp, deaths, cnt, done);
    }
    sort_kernel<<<2, 1024, 0, stream>>>(deaths);
    finalize_kernel<<<1, 256, 0, stream>>>(deaths, partials, 512, out);
}